// Round 4
// baseline (1863.697 us; speedup 1.0000x reference)
//
#include <hip/hip_runtime.h>
#include <hip/hip_bf16.h>
#include <math.h>

#define N_NODES  50000
#define IN_DIM   128
#define HIDDEN   64
#define OUT_DIM  3
#define HEADS1   4
#define E_RAW    400000
#define E_TOT    450000   // raw edges + one self loop per node
#define NEG_SLOPE 0.2f

// ---- portable float atomics via integer CAS (works on any memory type) ----
static __device__ __forceinline__ void atomAddF(float* addr, float val) {
    unsigned int* ua = (unsigned int*)addr;
    unsigned int old = *ua, assumed;
    do {
        assumed = old;
        float f = __uint_as_float(assumed) + val;
        old = atomicCAS(ua, assumed, __float_as_uint(f));
    } while (old != assumed);
}
static __device__ __forceinline__ void atomMaxF(float* addr, float val) {
    unsigned int* ua = (unsigned int*)addr;
    unsigned int old = *ua;
    while (__uint_as_float(old) < val) {
        unsigned int assumed = old;
        old = atomicCAS(ua, assumed, __float_as_uint(val));
        if (old == assumed) break;
    }
}

// ---- edge fetch, robust to int32 vs int64 storage, indices clamped ----
static __device__ __forceinline__ void get_edge(const int* __restrict__ ei, int is64,
                                                int e, int& s, int& d) {
    if (e >= E_RAW) { s = d = e - E_RAW; return; }   // self loop
    if (is64) { s = ei[2 * e]; d = ei[2 * E_RAW + 2 * e]; }
    else      { s = ei[e];     d = ei[E_RAW + e]; }
    s = min(max(s, 0), N_NODES - 1);
    d = min(max(d, 0), N_NODES - 1);
}

// Detect int64 storage: high words of int64 pairs are all 0 for values < 2^31.
__global__ void detect_int64_kernel(const int* __restrict__ ei, int* __restrict__ flag) {
    __shared__ int any_nonzero;
    if (threadIdx.x == 0) any_nonzero = 0;
    __syncthreads();
    for (int i = threadIdx.x; i < 8192; i += blockDim.x) {
        int k = i * 48;                    // 2k+1 < 786,433: in-bounds for both layouts
        if (ei[2 * k + 1] != 0) any_nonzero = 1;   // benign race
    }
    __syncthreads();
    if (threadIdx.x == 0) flag[0] = (any_nonzero == 0) ? 1 : 0;
}

__global__ void fill_kernel(float* __restrict__ p, float v, int n) {
    int i = blockIdx.x * blockDim.x + threadIdx.x;
    if (i < n) p[i] = v;
}

// ---- GEMM: C(f32)[M,64] = A(f32)[M,K] @ B(f32)[K, bcol:bcol+64], B row-stride ldb ----
__global__ void gemm64_kernel(const float* __restrict__ A, const float* __restrict__ B,
                              float* __restrict__ C, int M, int K, int ldb, int bcol) {
    __shared__ float As[16][68];
    __shared__ float Bs[16][68];
    const int row0 = blockIdx.x * 64;
    const int tid  = threadIdx.x;
    const int tm   = (tid / 16) * 4;
    const int tn   = (tid % 16) * 4;
    float acc[4][4] = {};
    for (int k0 = 0; k0 < K; k0 += 16) {
        for (int i = tid; i < 64 * 16; i += 256) {
            int m = i / 16, k = i % 16;
            int gm = row0 + m;
            As[k][m] = (gm < M) ? A[gm * K + k0 + k] : 0.0f;
        }
        for (int i = tid; i < 16 * 64; i += 256) {
            int k = i / 64, n = i % 64;
            Bs[k][n] = B[(k0 + k) * ldb + bcol + n];
        }
        __syncthreads();
        #pragma unroll
        for (int k = 0; k < 16; k++) {
            float a[4], b[4];
            #pragma unroll
            for (int i = 0; i < 4; i++) a[i] = As[k][tm + i];
            #pragma unroll
            for (int j = 0; j < 4; j++) b[j] = Bs[k][tn + j];
            #pragma unroll
            for (int i = 0; i < 4; i++)
                #pragma unroll
                for (int j = 0; j < 4; j++) acc[i][j] += a[i] * b[j];
        }
        __syncthreads();
    }
    for (int i = 0; i < 4; i++) {
        int gm = row0 + tm + i;
        if (gm < M) {
            for (int j = 0; j < 4; j++) C[gm * 64 + tn + j] = acc[i][j];
        }
    }
}

// ---- fused layer-2 accumulate: C(f32)[M,64] += elu(agg + bias) @ W2[brow:brow+64, :] ----
__global__ void gemm64_acc_elu_kernel(const float* __restrict__ agg,
                                      const float* __restrict__ bias,   // 64 entries
                                      const float* __restrict__ B,      // W2 [256,64]
                                      float* __restrict__ C, int M, int brow) {
    __shared__ float As[16][68];
    __shared__ float Bs[16][68];
    const int row0 = blockIdx.x * 64;
    const int tid  = threadIdx.x;
    const int tm   = (tid / 16) * 4;
    const int tn   = (tid % 16) * 4;
    float acc[4][4] = {};
    for (int k0 = 0; k0 < 64; k0 += 16) {
        for (int i = tid; i < 64 * 16; i += 256) {
            int m = i / 16, k = i % 16;
            int gm = row0 + m;
            float v = (gm < M) ? (agg[gm * 64 + k0 + k] + bias[k0 + k]) : 0.0f;
            As[k][m] = (v > 0.f) ? v : expm1f(v);
        }
        for (int i = tid; i < 16 * 64; i += 256) {
            int k = i / 64, n = i % 64;
            Bs[k][n] = B[(brow + k0 + k) * 64 + n];
        }
        __syncthreads();
        #pragma unroll
        for (int k = 0; k < 16; k++) {
            float a[4], b[4];
            #pragma unroll
            for (int i = 0; i < 4; i++) a[i] = As[k][tm + i];
            #pragma unroll
            for (int j = 0; j < 4; j++) b[j] = Bs[k][tn + j];
            #pragma unroll
            for (int i = 0; i < 4; i++)
                #pragma unroll
                for (int j = 0; j < 4; j++) acc[i][j] += a[i] * b[j];
        }
        __syncthreads();
    }
    for (int i = 0; i < 4; i++) {
        int gm = row0 + tm + i;
        if (gm < M) {
            for (int j = 0; j < 4; j++) C[gm * 64 + tn + j] += acc[i][j];
        }
    }
}

// ---- attention scores (single head): as[n] = <h[n,:], att_s>, ad[n] = <h[n,:], att_d> ----
__global__ void attn_score_kernel(const float* __restrict__ hfeat,
                                  const float* __restrict__ att_s,
                                  const float* __restrict__ att_d,
                                  float* __restrict__ as_, float* __restrict__ ad_) {
    int n = blockIdx.x * blockDim.x + threadIdx.x;
    if (n >= N_NODES) return;
    float s = 0.f, d = 0.f;
    for (int c = 0; c < HIDDEN; c++) {
        float v = hfeat[(size_t)n * HIDDEN + c];
        s += v * att_s[c];
        d += v * att_d[c];
    }
    as_[n] = s;
    ad_[n] = d;
}

// ---- pass 1: e = leaky_relu(as[src]+ad[dst]); segment max into m ----
__global__ void edge_pass1_kernel(const int* __restrict__ ei, const int* __restrict__ flag,
                                  const float* __restrict__ as_, const float* __restrict__ ad_,
                                  float* __restrict__ ebuf, float* __restrict__ m) {
    int e = blockIdx.x * blockDim.x + threadIdx.x;
    if (e >= E_TOT) return;
    int s, d;
    get_edge(ei, flag[0], e, s, d);
    float v = as_[s] + ad_[d];
    v = (v > 0.f) ? v : NEG_SLOPE * v;
    ebuf[e] = v;
    atomMaxF(&m[d], v);
}

// ---- pass 2: ex = exp(e - m[dst]); segment sum into denom ----
__global__ void edge_pass2_kernel(const int* __restrict__ ei, const int* __restrict__ flag,
                                  float* __restrict__ ebuf, const float* __restrict__ m,
                                  float* __restrict__ denom) {
    int e = blockIdx.x * blockDim.x + threadIdx.x;
    if (e >= E_TOT) return;
    int s, d;
    get_edge(ei, flag[0], e, s, d);
    float ex = expf(ebuf[e] - m[d]);
    ebuf[e] = ex;
    atomAddF(&denom[d], ex);
}

// ---- pass 3: agg[dst,:] += alpha * h[src,:] ; one edge per block (64 thr) ----
__global__ void edge_pass3_kernel(const int* __restrict__ ei, const int* __restrict__ flag,
                                  const float* __restrict__ ebuf, const float* __restrict__ denom,
                                  const float* __restrict__ hfeat, float* __restrict__ agg) {
    int e = blockIdx.x;
    int c = threadIdx.x;           // 64 threads
    int s, d;
    get_edge(ei, flag[0], e, s, d);
    float alpha = ebuf[e] / (denom[d] + 1e-16f);
    if (!isfinite(alpha)) alpha = 0.f;    // diagnostic guard
    atomAddF(&agg[(size_t)d * HIDDEN + c], alpha * hfeat[(size_t)s * HIDDEN + c]);
}

// ---- out(f32)[N,64] = elu(agg + bias) ----
__global__ void bias_elu_kernel(const float* __restrict__ agg,
                                const float* __restrict__ bias,
                                float* __restrict__ out) {
    int i = blockIdx.x * blockDim.x + threadIdx.x;
    if (i >= N_NODES * HIDDEN) return;
    int c = i % HIDDEN;
    float v = agg[i] + bias[c];
    out[i] = (v > 0.f) ? v : expm1f(v);
}

// ---- final projection to OUT_DIM, fp32 output ----
__global__ void out_linear_kernel(const float* __restrict__ hfeat,
                                  const float* __restrict__ Wout,
                                  const float* __restrict__ bout,
                                  float* __restrict__ out) {
    int n = blockIdx.x * blockDim.x + threadIdx.x;
    if (n >= N_NODES) return;
    float acc[OUT_DIM];
    #pragma unroll
    for (int o = 0; o < OUT_DIM; o++) acc[o] = bout[o];
    for (int c = 0; c < HIDDEN; c++) {
        float v = hfeat[(size_t)n * HIDDEN + c];
        #pragma unroll
        for (int o = 0; o < OUT_DIM; o++) acc[o] += v * Wout[c * OUT_DIM + o];
    }
    #pragma unroll
    for (int o = 0; o < OUT_DIM; o++) out[n * OUT_DIM + o] = acc[o];
}

extern "C" void kernel_launch(void* const* d_in, const int* in_sizes, int n_in,
                              void* d_out, int out_size, void* d_ws, size_t ws_size,
                              hipStream_t stream) {
    const float* x    = (const float*)d_in[0];    // [50000,128] fp32
    const int*   ei   = (const int*)d_in[1];      // [2,400000] int32 or int64 (detected)
    const float* W1   = (const float*)d_in[2];    // [128,256]
    const float* as1  = (const float*)d_in[3];    // [4,64]
    const float* ad1  = (const float*)d_in[4];    // [4,64]
    const float* b1   = (const float*)d_in[5];    // [256]
    const float* W2   = (const float*)d_in[6];    // [256,64]
    const float* as2  = (const float*)d_in[7];    // [1,64]
    const float* ad2  = (const float*)d_in[8];    // [1,64]
    const float* b2v  = (const float*)d_in[9];    // [64]
    const float* Wout = (const float*)d_in[10];   // [64,3]
    const float* bout = (const float*)d_in[11];   // [3]
    float* out = (float*)d_out;                   // [50000,3] fp32

    // ---- workspace layout (~41 MB), flag at base ----
    float* ws   = (float*)d_ws;
    int*   flag = (int*)ws;                          // 16 floats reserved
    float* asb  = ws + 16;                           // 50,000
    float* adb  = asb + N_NODES;                     // 50,000
    float* mbuf = adb + N_NODES;                     // 50,000
    float* dbuf = mbuf + N_NODES;                    // 50,000
    float* ebuf = dbuf + N_NODES;                    // 450,000
    float* h1h  = ebuf + E_TOT;                      // 3,200,000 (per-head feats; later L2 out)
    float* aggh = h1h + (size_t)N_NODES * HIDDEN;    // 3,200,000 (per-head agg)
    float* h2   = aggh + (size_t)N_NODES * HIDDEN;   // 3,200,000 (accumulated L2 features)

    const float NEG_INF = -INFINITY;
    const int EB = (E_TOT + 255) / 256;
    const int NB = (N_NODES + 255) / 256;
    const int CB = (N_NODES * HIDDEN + 255) / 256;
    const int GB = (N_NODES + 63) / 64;

    detect_int64_kernel<<<1, 256, 0, stream>>>(ei, flag);
    hipMemsetAsync(h2, 0, (size_t)N_NODES * HIDDEN * sizeof(float), stream);

    // ===== layer 1 per head (GATConv 128 -> 64, heads=4), fused into L2-input GEMM =====
    for (int h = 0; h < HEADS1; h++) {
        gemm64_kernel<<<GB, 256, 0, stream>>>(x, W1, h1h, N_NODES, IN_DIM, HEADS1 * HIDDEN, h * HIDDEN);
        attn_score_kernel<<<NB, 256, 0, stream>>>(h1h, as1 + h * HIDDEN, ad1 + h * HIDDEN, asb, adb);
        fill_kernel<<<NB, 256, 0, stream>>>(mbuf, NEG_INF, N_NODES);
        hipMemsetAsync(dbuf, 0, (size_t)N_NODES * sizeof(float), stream);
        hipMemsetAsync(aggh, 0, (size_t)N_NODES * HIDDEN * sizeof(float), stream);
        edge_pass1_kernel<<<EB, 256, 0, stream>>>(ei, flag, asb, adb, ebuf, mbuf);
        edge_pass2_kernel<<<EB, 256, 0, stream>>>(ei, flag, ebuf, mbuf, dbuf);
        edge_pass3_kernel<<<E_TOT, HIDDEN, 0, stream>>>(ei, flag, ebuf, dbuf, h1h, aggh);
        // h2 += elu(aggh + b1[h]) @ W2[h*64 : h*64+64, :]
        gemm64_acc_elu_kernel<<<GB, 256, 0, stream>>>(aggh, b1 + h * HIDDEN, W2, h2, N_NODES, h * HIDDEN);
    }

    // ===== layer 2 (GATConv 256 -> 64, heads=1); h2 already holds elu(out1) @ W2 =====
    attn_score_kernel<<<NB, 256, 0, stream>>>(h2, as2, ad2, asb, adb);
    fill_kernel<<<NB, 256, 0, stream>>>(mbuf, NEG_INF, N_NODES);
    hipMemsetAsync(dbuf, 0, (size_t)N_NODES * sizeof(float), stream);
    hipMemsetAsync(aggh, 0, (size_t)N_NODES * HIDDEN * sizeof(float), stream);
    edge_pass1_kernel<<<EB, 256, 0, stream>>>(ei, flag, asb, adb, ebuf, mbuf);
    edge_pass2_kernel<<<EB, 256, 0, stream>>>(ei, flag, ebuf, mbuf, dbuf);
    edge_pass3_kernel<<<E_TOT, HIDDEN, 0, stream>>>(ei, flag, ebuf, dbuf, h2, aggh);
    bias_elu_kernel<<<CB, 256, 0, stream>>>(aggh, b2v, h1h);   // h1h <- out2 (fp32)

    // ===== output projection =====
    out_linear_kernel<<<NB, 256, 0, stream>>>(h1h, Wout, bout, out);
}

// Round 5
// 693.877 us; speedup vs baseline: 2.6859x; 2.6859x over previous
//
#include <hip/hip_runtime.h>
#include <hip/hip_bf16.h>
#include <math.h>

#define N_NODES  50000
#define IN_DIM   128
#define HIDDEN   64
#define OUT_DIM  3
#define HEADS1   4
#define E_RAW    400000
#define E_TOT    450000   // raw edges + one self loop per node
#define NEG_SLOPE 0.2f

// ---- edge fetch, robust to int32 vs int64 storage, indices clamped ----
static __device__ __forceinline__ void get_edge(const int* __restrict__ ei, int is64,
                                                int e, int& s, int& d) {
    if (e >= E_RAW) { s = d = e - E_RAW; return; }   // self loop
    if (is64) { s = ei[2 * e]; d = ei[2 * E_RAW + 2 * e]; }
    else      { s = ei[e];     d = ei[E_RAW + e]; }
    s = min(max(s, 0), N_NODES - 1);
    d = min(max(d, 0), N_NODES - 1);
}

// Detect int64 storage: high words of int64 pairs are all 0 for values < 2^31.
__global__ void detect_int64_kernel(const int* __restrict__ ei, int* __restrict__ flag) {
    __shared__ int any_nonzero;
    if (threadIdx.x == 0) any_nonzero = 0;
    __syncthreads();
    for (int i = threadIdx.x; i < 8192; i += blockDim.x) {
        int k = i * 48;                    // 2k+1 < 786,433: in-bounds for both layouts
        if (ei[2 * k + 1] != 0) any_nonzero = 1;   // benign race
    }
    __syncthreads();
    if (threadIdx.x == 0) flag[0] = (any_nonzero == 0) ? 1 : 0;
}

// ================= CSR construction (once per launch, graph is static) =================
__global__ void count_deg_kernel(const int* __restrict__ ei, const int* __restrict__ flag,
                                 int* __restrict__ deg) {
    int e = blockIdx.x * blockDim.x + threadIdx.x;
    if (e >= E_TOT) return;
    int s, d;
    get_edge(ei, flag[0], e, s, d);
    atomicAdd(&deg[d], 1);
}

// single-block exclusive scan: row_ptr[0]=0, row_ptr[i+1]=sum(deg[0..i])
__global__ void scan_kernel(const int* __restrict__ deg, int* __restrict__ row_ptr) {
    __shared__ int buf[1024];
    __shared__ int carry_s;
    if (threadIdx.x == 0) { carry_s = 0; row_ptr[0] = 0; }
    __syncthreads();
    for (int base = 0; base < N_NODES; base += 1024) {
        int i = base + threadIdx.x;
        buf[threadIdx.x] = (i < N_NODES) ? deg[i] : 0;
        __syncthreads();
        for (int off = 1; off < 1024; off <<= 1) {
            int t = (threadIdx.x >= off) ? buf[threadIdx.x - off] : 0;
            __syncthreads();
            buf[threadIdx.x] += t;
            __syncthreads();
        }
        int carry = carry_s;
        if (i < N_NODES) row_ptr[i + 1] = carry + buf[threadIdx.x];
        __syncthreads();
        if (threadIdx.x == 1023) carry_s = carry + buf[1023];
        __syncthreads();
    }
}

__global__ void copy_int_kernel(const int* __restrict__ a, int* __restrict__ b, int n) {
    int i = blockIdx.x * blockDim.x + threadIdx.x;
    if (i < n) b[i] = a[i];
}

__global__ void scatter_kernel(const int* __restrict__ ei, const int* __restrict__ flag,
                               int* __restrict__ cursor, int* __restrict__ csr_src) {
    int e = blockIdx.x * blockDim.x + threadIdx.x;
    if (e >= E_TOT) return;
    int s, d;
    get_edge(ei, flag[0], e, s, d);
    int pos = atomicAdd(&cursor[d], 1);
    csr_src[pos] = s;
}

// ================= GEMMs =================
// C(f32)[M,64] = A(f32)[M,K] @ B(f32)[K, bcol:bcol+64], B row-stride ldb
__global__ void gemm64_kernel(const float* __restrict__ A, const float* __restrict__ B,
                              float* __restrict__ C, int M, int K, int ldb, int bcol) {
    __shared__ float As[16][68];
    __shared__ float Bs[16][68];
    const int row0 = blockIdx.x * 64;
    const int tid  = threadIdx.x;
    const int tm   = (tid / 16) * 4;
    const int tn   = (tid % 16) * 4;
    float acc[4][4] = {};
    for (int k0 = 0; k0 < K; k0 += 16) {
        for (int i = tid; i < 64 * 16; i += 256) {
            int m = i / 16, k = i % 16;
            int gm = row0 + m;
            As[k][m] = (gm < M) ? A[gm * K + k0 + k] : 0.0f;
        }
        for (int i = tid; i < 16 * 64; i += 256) {
            int k = i / 64, n = i % 64;
            Bs[k][n] = B[(k0 + k) * ldb + bcol + n];
        }
        __syncthreads();
        #pragma unroll
        for (int k = 0; k < 16; k++) {
            float a[4], b[4];
            #pragma unroll
            for (int i = 0; i < 4; i++) a[i] = As[k][tm + i];
            #pragma unroll
            for (int j = 0; j < 4; j++) b[j] = Bs[k][tn + j];
            #pragma unroll
            for (int i = 0; i < 4; i++)
                #pragma unroll
                for (int j = 0; j < 4; j++) acc[i][j] += a[i] * b[j];
        }
        __syncthreads();
    }
    for (int i = 0; i < 4; i++) {
        int gm = row0 + tm + i;
        if (gm < M) {
            for (int j = 0; j < 4; j++) C[gm * 64 + tn + j] = acc[i][j];
        }
    }
}

// fused layer-2 accumulate: C(f32)[M,64] += elu(agg + bias) @ W2[brow:brow+64, :]
__global__ void gemm64_acc_elu_kernel(const float* __restrict__ agg,
                                      const float* __restrict__ bias,   // 64 entries
                                      const float* __restrict__ B,      // W2 [256,64]
                                      float* __restrict__ C, int M, int brow) {
    __shared__ float As[16][68];
    __shared__ float Bs[16][68];
    const int row0 = blockIdx.x * 64;
    const int tid  = threadIdx.x;
    const int tm   = (tid / 16) * 4;
    const int tn   = (tid % 16) * 4;
    float acc[4][4] = {};
    for (int k0 = 0; k0 < 64; k0 += 16) {
        for (int i = tid; i < 64 * 16; i += 256) {
            int m = i / 16, k = i % 16;
            int gm = row0 + m;
            float v = (gm < M) ? (agg[gm * 64 + k0 + k] + bias[k0 + k]) : 0.0f;
            As[k][m] = (v > 0.f) ? v : expm1f(v);
        }
        for (int i = tid; i < 16 * 64; i += 256) {
            int k = i / 64, n = i % 64;
            Bs[k][n] = B[(brow + k0 + k) * 64 + n];
        }
        __syncthreads();
        #pragma unroll
        for (int k = 0; k < 16; k++) {
            float a[4], b[4];
            #pragma unroll
            for (int i = 0; i < 4; i++) a[i] = As[k][tm + i];
            #pragma unroll
            for (int j = 0; j < 4; j++) b[j] = Bs[k][tn + j];
            #pragma unroll
            for (int i = 0; i < 4; i++)
                #pragma unroll
                for (int j = 0; j < 4; j++) acc[i][j] += a[i] * b[j];
        }
        __syncthreads();
    }
    for (int i = 0; i < 4; i++) {
        int gm = row0 + tm + i;
        if (gm < M) {
            for (int j = 0; j < 4; j++) C[gm * 64 + tn + j] += acc[i][j];
        }
    }
}

// ---- attention scores (single head) ----
__global__ void attn_score_kernel(const float* __restrict__ hfeat,
                                  const float* __restrict__ att_s,
                                  const float* __restrict__ att_d,
                                  float* __restrict__ as_, float* __restrict__ ad_) {
    int n = blockIdx.x * blockDim.x + threadIdx.x;
    if (n >= N_NODES) return;
    float s = 0.f, d = 0.f;
    for (int c = 0; c < HIDDEN; c++) {
        float v = hfeat[(size_t)n * HIDDEN + c];
        s += v * att_s[c];
        d += v * att_d[c];
    }
    as_[n] = s;
    ad_[n] = d;
}

// ================= fused GAT propagation: softmax + aggregate, no atomics =================
// one wave (64 lanes) per dst node; lane = channel; online softmax in registers.
__global__ void __launch_bounds__(256) gat_agg_kernel(
        const int* __restrict__ row_ptr, const int* __restrict__ csr_src,
        const float* __restrict__ as_, const float* __restrict__ ad_,
        const float* __restrict__ hfeat, float* __restrict__ agg) {
    int wave = threadIdx.x >> 6;
    int c    = threadIdx.x & 63;
    int n    = blockIdx.x * 4 + wave;
    if (n >= N_NODES) return;
    int begin = row_ptr[n], end = row_ptr[n + 1];
    float ad_n = ad_[n];
    float m = -INFINITY, l = 0.f, acc = 0.f;
    for (int j = begin; j < end; j++) {
        int s = csr_src[j];                       // wave-uniform -> scalar load
        float e = as_[s] + ad_n;
        e = (e > 0.f) ? e : NEG_SLOPE * e;
        float mnew = fmaxf(m, e);
        float scale = __expf(m - mnew);           // first iter: exp(-inf)=0
        float p = __expf(e - mnew);
        l = l * scale + p;
        acc = acc * scale + p * hfeat[(size_t)s * HIDDEN + c];
        m = mnew;
    }
    agg[(size_t)n * HIDDEN + c] = acc / (l + 1e-16f);
}

// ---- out(f32)[N,64] = elu(agg + bias) ----
__global__ void bias_elu_kernel(const float* __restrict__ agg,
                                const float* __restrict__ bias,
                                float* __restrict__ out) {
    int i = blockIdx.x * blockDim.x + threadIdx.x;
    if (i >= N_NODES * HIDDEN) return;
    int c = i % HIDDEN;
    float v = agg[i] + bias[c];
    out[i] = (v > 0.f) ? v : expm1f(v);
}

// ---- final projection to OUT_DIM, fp32 output ----
__global__ void out_linear_kernel(const float* __restrict__ hfeat,
                                  const float* __restrict__ Wout,
                                  const float* __restrict__ bout,
                                  float* __restrict__ out) {
    int n = blockIdx.x * blockDim.x + threadIdx.x;
    if (n >= N_NODES) return;
    float acc[OUT_DIM];
    #pragma unroll
    for (int o = 0; o < OUT_DIM; o++) acc[o] = bout[o];
    for (int c = 0; c < HIDDEN; c++) {
        float v = hfeat[(size_t)n * HIDDEN + c];
        #pragma unroll
        for (int o = 0; o < OUT_DIM; o++) acc[o] += v * Wout[c * OUT_DIM + o];
    }
    #pragma unroll
    for (int o = 0; o < OUT_DIM; o++) out[n * OUT_DIM + o] = acc[o];
}

extern "C" void kernel_launch(void* const* d_in, const int* in_sizes, int n_in,
                              void* d_out, int out_size, void* d_ws, size_t ws_size,
                              hipStream_t stream) {
    const float* x    = (const float*)d_in[0];    // [50000,128] fp32
    const int*   ei   = (const int*)d_in[1];      // [2,400000] int32/int64 (detected)
    const float* W1   = (const float*)d_in[2];    // [128,256]
    const float* as1  = (const float*)d_in[3];    // [4,64]
    const float* ad1  = (const float*)d_in[4];    // [4,64]
    const float* b1   = (const float*)d_in[5];    // [256]
    const float* W2   = (const float*)d_in[6];    // [256,64]
    const float* as2  = (const float*)d_in[7];    // [1,64]
    const float* ad2  = (const float*)d_in[8];    // [1,64]
    const float* b2v  = (const float*)d_in[9];    // [64]
    const float* Wout = (const float*)d_in[10];   // [64,3]
    const float* bout = (const float*)d_in[11];   // [3]
    float* out = (float*)d_out;                   // [50000,3] fp32

    // ---- workspace layout (~42 MB), flag at base ----
    float* ws   = (float*)d_ws;
    int*   flag = (int*)ws;                          // 16 floats reserved
    float* asb  = ws + 16;                           // 50,000
    float* adb  = asb + N_NODES;                     // 50,000
    float* h1h  = adb + N_NODES;                     // 3,200,000 (per-head feats; later L2 out)
    float* aggh = h1h + (size_t)N_NODES * HIDDEN;    // 3,200,000 (per-head agg)
    float* h2   = aggh + (size_t)N_NODES * HIDDEN;   // 3,200,000 (accumulated L2 features)
    int* deg     = (int*)(h2 + (size_t)N_NODES * HIDDEN);  // 50,000 (also scatter cursor)
    int* row_ptr = deg + N_NODES;                    // 50,001 (+pad)
    int* csr_src = row_ptr + N_NODES + 16;           // 450,000

    const int EB = (E_TOT + 255) / 256;
    const int NB = (N_NODES + 255) / 256;
    const int CB = (N_NODES * HIDDEN + 255) / 256;
    const int GB = (N_NODES + 63) / 64;
    const int AB = (N_NODES + 3) / 4;                // gat_agg: 4 nodes/block

    detect_int64_kernel<<<1, 256, 0, stream>>>(ei, flag);
    hipMemsetAsync(h2, 0, (size_t)N_NODES * HIDDEN * sizeof(float), stream);

    // ---- CSR build (deg -> row_ptr -> scatter), reused by all 5 propagation passes ----
    hipMemsetAsync(deg, 0, (size_t)N_NODES * sizeof(int), stream);
    count_deg_kernel<<<EB, 256, 0, stream>>>(ei, flag, deg);
    scan_kernel<<<1, 1024, 0, stream>>>(deg, row_ptr);
    copy_int_kernel<<<NB, 256, 0, stream>>>(row_ptr, deg, N_NODES);   // deg becomes cursor
    scatter_kernel<<<EB, 256, 0, stream>>>(ei, flag, deg, csr_src);

    // ===== layer 1 per head (GATConv 128 -> 64, heads=4), fused into L2-input GEMM =====
    for (int h = 0; h < HEADS1; h++) {
        gemm64_kernel<<<GB, 256, 0, stream>>>(x, W1, h1h, N_NODES, IN_DIM, HEADS1 * HIDDEN, h * HIDDEN);
        attn_score_kernel<<<NB, 256, 0, stream>>>(h1h, as1 + h * HIDDEN, ad1 + h * HIDDEN, asb, adb);
        gat_agg_kernel<<<AB, 256, 0, stream>>>(row_ptr, csr_src, asb, adb, h1h, aggh);
        // h2 += elu(aggh + b1[h]) @ W2[h*64 : h*64+64, :]
        gemm64_acc_elu_kernel<<<GB, 256, 0, stream>>>(aggh, b1 + h * HIDDEN, W2, h2, N_NODES, h * HIDDEN);
    }

    // ===== layer 2 (GATConv 256 -> 64, heads=1); h2 already holds elu(out1) @ W2 =====
    attn_score_kernel<<<NB, 256, 0, stream>>>(h2, as2, ad2, asb, adb);
    gat_agg_kernel<<<AB, 256, 0, stream>>>(row_ptr, csr_src, asb, adb, h2, aggh);
    bias_elu_kernel<<<CB, 256, 0, stream>>>(aggh, b2v, h1h);   // h1h <- out2 (fp32)

    // ===== output projection =====
    out_linear_kernel<<<NB, 256, 0, stream>>>(h1h, Wout, bout, out);
}

// Round 6
// 606.683 us; speedup vs baseline: 3.0719x; 1.1437x over previous
//
#include <hip/hip_runtime.h>
#include <hip/hip_bf16.h>
#include <math.h>

#define N_NODES  50000
#define IN_DIM   128
#define HIDDEN   64
#define OUT_DIM  3
#define HEADS1   4
#define E_RAW    400000
#define E_TOT    450000   // raw edges + one self loop per node
#define NEG_SLOPE 0.2f
#define SCAN_CHUNK 1024
#define N_CHUNKS ((N_NODES + SCAN_CHUNK - 1) / SCAN_CHUNK)   // 49

// ---- edge fetch, robust to int32 vs int64 storage, indices clamped ----
static __device__ __forceinline__ void get_edge(const int* __restrict__ ei, int is64,
                                                int e, int& s, int& d) {
    if (e >= E_RAW) { s = d = e - E_RAW; return; }   // self loop
    if (is64) { s = ei[2 * e]; d = ei[2 * E_RAW + 2 * e]; }
    else      { s = ei[e];     d = ei[E_RAW + e]; }
    s = min(max(s, 0), N_NODES - 1);
    d = min(max(d, 0), N_NODES - 1);
}

// Detect int64 storage: high words of int64 pairs are all 0 for values < 2^31.
__global__ void detect_int64_kernel(const int* __restrict__ ei, int* __restrict__ flag) {
    __shared__ int any_nonzero;
    if (threadIdx.x == 0) any_nonzero = 0;
    __syncthreads();
    for (int i = threadIdx.x; i < 8192; i += blockDim.x) {
        int k = i * 48;                    // 2k+1 < 786,433: in-bounds for both layouts
        if (ei[2 * k + 1] != 0) any_nonzero = 1;   // benign race
    }
    __syncthreads();
    if (threadIdx.x == 0) flag[0] = (any_nonzero == 0) ? 1 : 0;
}

// ================= CSR construction (once per launch, graph is static) =================
__global__ void count_deg_kernel(const int* __restrict__ ei, const int* __restrict__ flag,
                                 int* __restrict__ deg) {
    int e = blockIdx.x * blockDim.x + threadIdx.x;
    if (e >= E_TOT) return;
    int s, d;
    get_edge(ei, flag[0], e, s, d);
    atomicAdd(&deg[d], 1);
}

// hierarchical scan, stage 1: per-chunk inclusive scan + chunk totals
__global__ void scan_local_kernel(const int* __restrict__ deg, int* __restrict__ row_ptr,
                                  int* __restrict__ bsums) {
    __shared__ int buf[SCAN_CHUNK];
    int base = blockIdx.x * SCAN_CHUNK;
    int i = base + threadIdx.x;
    buf[threadIdx.x] = (i < N_NODES) ? deg[i] : 0;
    __syncthreads();
    for (int off = 1; off < SCAN_CHUNK; off <<= 1) {
        int t = (threadIdx.x >= off) ? buf[threadIdx.x - off] : 0;
        __syncthreads();
        buf[threadIdx.x] += t;
        __syncthreads();
    }
    if (i < N_NODES) row_ptr[i + 1] = buf[threadIdx.x];   // local inclusive
    if (threadIdx.x == SCAN_CHUNK - 1) bsums[blockIdx.x] = buf[SCAN_CHUNK - 1];
    if (blockIdx.x == 0 && threadIdx.x == 0) row_ptr[0] = 0;
}

// stage 2: exclusive scan of the 49 chunk totals (single wave-ish block)
__global__ void scan_bsums_kernel(int* __restrict__ bsums) {
    __shared__ int buf[64];
    int i = threadIdx.x;
    buf[i] = (i < N_CHUNKS) ? bsums[i] : 0;
    __syncthreads();
    for (int off = 1; off < 64; off <<= 1) {
        int t = (i >= off) ? buf[i - off] : 0;
        __syncthreads();
        buf[i] += t;
        __syncthreads();
    }
    if (i < N_CHUNKS) bsums[i] = (i == 0) ? 0 : buf[i - 1];
}

// stage 3: add chunk offsets
__global__ void scan_add_kernel(int* __restrict__ row_ptr, const int* __restrict__ bsums) {
    int i = blockIdx.x * blockDim.x + threadIdx.x;
    if (i < N_NODES) row_ptr[i + 1] += bsums[i / SCAN_CHUNK];
}

__global__ void copy_int_kernel(const int* __restrict__ a, int* __restrict__ b, int n) {
    int i = blockIdx.x * blockDim.x + threadIdx.x;
    if (i < n) b[i] = a[i];
}

__global__ void scatter_kernel(const int* __restrict__ ei, const int* __restrict__ flag,
                               int* __restrict__ cursor, int* __restrict__ csr_src) {
    int e = blockIdx.x * blockDim.x + threadIdx.x;
    if (e >= E_TOT) return;
    int s, d;
    get_edge(ei, flag[0], e, s, d);
    int pos = atomicAdd(&cursor[d], 1);
    csr_src[pos] = s;
}

// ================= GEMMs: tile 128x64, 256 threads, 8x4 micro-tile =================
// C(f32)[M,64] = A(f32)[M,K] @ B(f32)[K, bcol:bcol+64]  (B row stride ldb; K % 16 == 0)
__global__ void __launch_bounds__(256) gemm128_kernel(
        const float* __restrict__ A, const float* __restrict__ B,
        float* __restrict__ C, int M, int K, int ldb, int bcol) {
    __shared__ float As[16][132];
    __shared__ float Bs[16][68];
    const int row0 = blockIdx.x * 128;
    const int tid = threadIdx.x;
    const int tm = (tid >> 4) * 8;     // row group: 16 groups x 8 rows
    const int tn = (tid & 15) * 4;     // col group: 16 groups x 4 cols
    float acc[8][4] = {};
    for (int k0 = 0; k0 < K; k0 += 16) {
        #pragma unroll
        for (int r = 0; r < 2; r++) {          // A: 128 rows x 16 k, transposed store
            int idx = tid * 2 + r;             // 0..511
            int m = idx >> 2;
            int q = (idx & 3) * 4;
            int gm = row0 + m;
            float4 v = make_float4(0.f, 0.f, 0.f, 0.f);
            if (gm < M) v = *(const float4*)(A + (size_t)gm * K + k0 + q);
            As[q + 0][m] = v.x; As[q + 1][m] = v.y; As[q + 2][m] = v.z; As[q + 3][m] = v.w;
        }
        {                                       // B: 16 k x 64 n
            int k = tid >> 4;
            int n = (tid & 15) * 4;
            *(float4*)&Bs[k][n] = *(const float4*)(B + (size_t)(k0 + k) * ldb + bcol + n);
        }
        __syncthreads();
        #pragma unroll
        for (int k = 0; k < 16; k++) {
            float a[8], b[4];
            #pragma unroll
            for (int i = 0; i < 8; i++) a[i] = As[k][tm + i];
            #pragma unroll
            for (int j = 0; j < 4; j++) b[j] = Bs[k][tn + j];
            #pragma unroll
            for (int i = 0; i < 8; i++)
                #pragma unroll
                for (int j = 0; j < 4; j++) acc[i][j] += a[i] * b[j];
        }
        __syncthreads();
    }
    #pragma unroll
    for (int i = 0; i < 8; i++) {
        int gm = row0 + tm + i;
        if (gm < M)
            *(float4*)(C + (size_t)gm * 64 + tn) =
                make_float4(acc[i][0], acc[i][1], acc[i][2], acc[i][3]);
    }
}

// C(f32)[M,64] += elu(agg + bias) @ W2[brow:brow+64, :]   (A staged through elu)
__global__ void __launch_bounds__(256) gemm128_acc_elu_kernel(
        const float* __restrict__ agg, const float* __restrict__ bias,
        const float* __restrict__ B, float* __restrict__ C, int M, int brow) {
    __shared__ float As[16][132];
    __shared__ float Bs[16][68];
    const int row0 = blockIdx.x * 128;
    const int tid = threadIdx.x;
    const int tm = (tid >> 4) * 8;
    const int tn = (tid & 15) * 4;
    float acc[8][4] = {};
    for (int k0 = 0; k0 < 64; k0 += 16) {
        #pragma unroll
        for (int r = 0; r < 2; r++) {
            int idx = tid * 2 + r;
            int m = idx >> 2;
            int q = (idx & 3) * 4;
            int gm = row0 + m;
            float4 v = make_float4(0.f, 0.f, 0.f, 0.f);
            if (gm < M) {
                v = *(const float4*)(agg + (size_t)gm * 64 + k0 + q);
                float4 bb = *(const float4*)(bias + k0 + q);
                v.x += bb.x; v.y += bb.y; v.z += bb.z; v.w += bb.w;
                v.x = (v.x > 0.f) ? v.x : expm1f(v.x);
                v.y = (v.y > 0.f) ? v.y : expm1f(v.y);
                v.z = (v.z > 0.f) ? v.z : expm1f(v.z);
                v.w = (v.w > 0.f) ? v.w : expm1f(v.w);
            }
            As[q + 0][m] = v.x; As[q + 1][m] = v.y; As[q + 2][m] = v.z; As[q + 3][m] = v.w;
        }
        {
            int k = tid >> 4;
            int n = (tid & 15) * 4;
            *(float4*)&Bs[k][n] = *(const float4*)(B + (size_t)(brow + k0 + k) * 64 + n);
        }
        __syncthreads();
        #pragma unroll
        for (int k = 0; k < 16; k++) {
            float a[8], b[4];
            #pragma unroll
            for (int i = 0; i < 8; i++) a[i] = As[k][tm + i];
            #pragma unroll
            for (int j = 0; j < 4; j++) b[j] = Bs[k][tn + j];
            #pragma unroll
            for (int i = 0; i < 8; i++)
                #pragma unroll
                for (int j = 0; j < 4; j++) acc[i][j] += a[i] * b[j];
        }
        __syncthreads();
    }
    #pragma unroll
    for (int i = 0; i < 8; i++) {
        int gm = row0 + tm + i;
        if (gm < M) {
            float4 c = *(float4*)(C + (size_t)gm * 64 + tn);
            c.x += acc[i][0]; c.y += acc[i][1]; c.z += acc[i][2]; c.w += acc[i][3];
            *(float4*)(C + (size_t)gm * 64 + tn) = c;
        }
    }
}

// ---- attention scores (single head), float4 loads ----
__global__ void attn_score_kernel(const float* __restrict__ hfeat,
                                  const float* __restrict__ att_s,
                                  const float* __restrict__ att_d,
                                  float* __restrict__ as_, float* __restrict__ ad_) {
    int n = blockIdx.x * blockDim.x + threadIdx.x;
    if (n >= N_NODES) return;
    const float4* row = (const float4*)(hfeat + (size_t)n * HIDDEN);
    const float4* aS = (const float4*)att_s;
    const float4* aD = (const float4*)att_d;
    float s = 0.f, d = 0.f;
    #pragma unroll
    for (int c = 0; c < HIDDEN / 4; c++) {
        float4 v = row[c], a = aS[c], b = aD[c];
        s += v.x * a.x + v.y * a.y + v.z * a.z + v.w * a.w;
        d += v.x * b.x + v.y * b.y + v.z * b.z + v.w * b.w;
    }
    as_[n] = s;
    ad_[n] = d;
}

// ================= fused GAT propagation: softmax + aggregate, no atomics =================
// one wave per dst node; lane = channel; online softmax in registers; 1-deep prefetch.
__global__ void __launch_bounds__(256) gat_agg_kernel(
        const int* __restrict__ row_ptr, const int* __restrict__ csr_src,
        const float* __restrict__ as_, const float* __restrict__ ad_,
        const float* __restrict__ hfeat, float* __restrict__ agg) {
    int wave = threadIdx.x >> 6;
    int c    = threadIdx.x & 63;
    int n    = blockIdx.x * 4 + wave;
    if (n >= N_NODES) return;
    int begin = row_ptr[n], end = row_ptr[n + 1];
    float ad_n = ad_[n];
    float m = -INFINITY, l = 0.f, acc = 0.f;
    int s = csr_src[begin];
    float asv = as_[s];
    float hv  = hfeat[(size_t)s * HIDDEN + c];
    for (int j = begin; j < end; j++) {
        int s2 = 0; float as2 = 0.f, hv2 = 0.f;
        if (j + 1 < end) {                       // prefetch next edge (wave-uniform branch)
            s2  = csr_src[j + 1];
            as2 = as_[s2];
            hv2 = hfeat[(size_t)s2 * HIDDEN + c];
        }
        float e = asv + ad_n;
        e = (e > 0.f) ? e : NEG_SLOPE * e;
        float mnew = fmaxf(m, e);
        float scale = __expf(m - mnew);          // first iter: exp(-inf)=0
        float p = __expf(e - mnew);
        l = l * scale + p;
        acc = acc * scale + p * hv;
        m = mnew;
        asv = as2; hv = hv2;
    }
    agg[(size_t)n * HIDDEN + c] = acc / (l + 1e-16f);
}

// ---- fused: out = (elu(agg + b2)) @ Wout + bout ----
__global__ void out_linear_elu_kernel(const float* __restrict__ agg,
                                      const float* __restrict__ bias,
                                      const float* __restrict__ Wout,
                                      const float* __restrict__ bout,
                                      float* __restrict__ out) {
    int n = blockIdx.x * blockDim.x + threadIdx.x;
    if (n >= N_NODES) return;
    float a0 = bout[0], a1 = bout[1], a2 = bout[2];
    for (int c = 0; c < HIDDEN; c++) {
        float v = agg[(size_t)n * HIDDEN + c] + bias[c];
        v = (v > 0.f) ? v : expm1f(v);
        a0 += v * Wout[c * OUT_DIM + 0];
        a1 += v * Wout[c * OUT_DIM + 1];
        a2 += v * Wout[c * OUT_DIM + 2];
    }
    out[n * OUT_DIM + 0] = a0;
    out[n * OUT_DIM + 1] = a1;
    out[n * OUT_DIM + 2] = a2;
}

extern "C" void kernel_launch(void* const* d_in, const int* in_sizes, int n_in,
                              void* d_out, int out_size, void* d_ws, size_t ws_size,
                              hipStream_t stream) {
    const float* x    = (const float*)d_in[0];    // [50000,128] fp32
    const int*   ei   = (const int*)d_in[1];      // [2,400000] int32/int64 (detected)
    const float* W1   = (const float*)d_in[2];    // [128,256]
    const float* as1  = (const float*)d_in[3];    // [4,64]
    const float* ad1  = (const float*)d_in[4];    // [4,64]
    const float* b1   = (const float*)d_in[5];    // [256]
    const float* W2   = (const float*)d_in[6];    // [256,64]
    const float* as2  = (const float*)d_in[7];    // [1,64]
    const float* ad2  = (const float*)d_in[8];    // [1,64]
    const float* b2v  = (const float*)d_in[9];    // [64]
    const float* Wout = (const float*)d_in[10];   // [64,3]
    const float* bout = (const float*)d_in[11];   // [3]
    float* out = (float*)d_out;                   // [50000,3] fp32

    // ---- workspace layout (~42 MB), flag at base ----
    float* ws   = (float*)d_ws;
    int*   flag = (int*)ws;                          // 16 floats reserved
    float* asb  = ws + 16;                           // 50,000
    float* adb  = asb + N_NODES;                     // 50,000
    float* h1h  = adb + N_NODES;                     // 3,200,000 (per-head feats)
    float* aggh = h1h + (size_t)N_NODES * HIDDEN;    // 3,200,000 (per-head agg)
    float* h2   = aggh + (size_t)N_NODES * HIDDEN;   // 3,200,000 (accumulated L2 features)
    int* deg     = (int*)(h2 + (size_t)N_NODES * HIDDEN);  // 50,000 (also scatter cursor)
    int* row_ptr = deg + N_NODES;                    // 50,001 (+pad)
    int* csr_src = row_ptr + N_NODES + 16;           // 450,000
    int* bsums   = csr_src + E_TOT;                  // 64

    const int EB = (E_TOT + 255) / 256;
    const int NB = (N_NODES + 255) / 256;
    const int GB = (N_NODES + 127) / 128;            // gemm 128-row tiles
    const int AB = (N_NODES + 3) / 4;                // gat_agg: 4 nodes/block

    detect_int64_kernel<<<1, 256, 0, stream>>>(ei, flag);
    hipMemsetAsync(h2, 0, (size_t)N_NODES * HIDDEN * sizeof(float), stream);

    // ---- CSR build: deg -> hierarchical scan -> scatter ----
    hipMemsetAsync(deg, 0, (size_t)N_NODES * sizeof(int), stream);
    count_deg_kernel<<<EB, 256, 0, stream>>>(ei, flag, deg);
    scan_local_kernel<<<N_CHUNKS, SCAN_CHUNK, 0, stream>>>(deg, row_ptr, bsums);
    scan_bsums_kernel<<<1, 64, 0, stream>>>(bsums);
    scan_add_kernel<<<NB, 256, 0, stream>>>(row_ptr, bsums);
    copy_int_kernel<<<NB, 256, 0, stream>>>(row_ptr, deg, N_NODES);   // deg becomes cursor
    scatter_kernel<<<EB, 256, 0, stream>>>(ei, flag, deg, csr_src);

    // ===== layer 1 per head (GATConv 128 -> 64, heads=4), fused into L2-input GEMM =====
    for (int h = 0; h < HEADS1; h++) {
        gemm128_kernel<<<GB, 256, 0, stream>>>(x, W1, h1h, N_NODES, IN_DIM, HEADS1 * HIDDEN, h * HIDDEN);
        attn_score_kernel<<<NB, 256, 0, stream>>>(h1h, as1 + h * HIDDEN, ad1 + h * HIDDEN, asb, adb);
        gat_agg_kernel<<<AB, 256, 0, stream>>>(row_ptr, csr_src, asb, adb, h1h, aggh);
        // h2 += elu(aggh + b1[h]) @ W2[h*64 : h*64+64, :]
        gemm128_acc_elu_kernel<<<GB, 256, 0, stream>>>(aggh, b1 + h * HIDDEN, W2, h2, N_NODES, h * HIDDEN);
    }

    // ===== layer 2 (GATConv 256 -> 64, heads=1); h2 already holds elu(out1) @ W2 =====
    attn_score_kernel<<<NB, 256, 0, stream>>>(h2, as2, ad2, asb, adb);
    gat_agg_kernel<<<AB, 256, 0, stream>>>(row_ptr, csr_src, asb, adb, h2, aggh);

    // ===== fused elu + output projection =====
    out_linear_elu_kernel<<<NB, 256, 0, stream>>>(aggh, b2v, Wout, bout, out);
}

// Round 7
// 551.442 us; speedup vs baseline: 3.3797x; 1.1002x over previous
//
#include <hip/hip_runtime.h>
#include <hip/hip_bf16.h>
#include <math.h>

#define N_NODES  50000
#define IN_DIM   128
#define HIDDEN   64
#define OUT_DIM  3
#define HEADS1   4
#define E_RAW    400000
#define E_TOT    450000   // raw edges + one self loop per node
#define NEG_SLOPE 0.2f
#define SCAN_CHUNK 1024
#define N_CHUNKS ((N_NODES + SCAN_CHUNK - 1) / SCAN_CHUNK)   // 49

// ---- edge fetch, robust to int32 vs int64 storage, indices clamped ----
static __device__ __forceinline__ void get_edge(const int* __restrict__ ei, int is64,
                                                int e, int& s, int& d) {
    if (e >= E_RAW) { s = d = e - E_RAW; return; }   // self loop
    if (is64) { s = ei[2 * e]; d = ei[2 * E_RAW + 2 * e]; }
    else      { s = ei[e];     d = ei[E_RAW + e]; }
    s = min(max(s, 0), N_NODES - 1);
    d = min(max(d, 0), N_NODES - 1);
}

// Detect int64 storage: high words of int64 pairs are all 0 for values < 2^31.
__global__ void detect_int64_kernel(const int* __restrict__ ei, int* __restrict__ flag) {
    __shared__ int any_nonzero;
    if (threadIdx.x == 0) any_nonzero = 0;
    __syncthreads();
    for (int i = threadIdx.x; i < 8192; i += blockDim.x) {
        int k = i * 48;                    // 2k+1 < 786,433: in-bounds for both layouts
        if (ei[2 * k + 1] != 0) any_nonzero = 1;   // benign race
    }
    __syncthreads();
    if (threadIdx.x == 0) flag[0] = (any_nonzero == 0) ? 1 : 0;
}

// ================= CSR construction (once per launch, graph is static) =================
__global__ void count_deg_kernel(const int* __restrict__ ei, const int* __restrict__ flag,
                                 int* __restrict__ deg) {
    int e = blockIdx.x * blockDim.x + threadIdx.x;
    if (e >= E_TOT) return;
    int s, d;
    get_edge(ei, flag[0], e, s, d);
    atomicAdd(&deg[d], 1);
}

// hierarchical scan, stage 1: per-chunk inclusive scan + chunk totals
__global__ void scan_local_kernel(const int* __restrict__ deg, int* __restrict__ row_ptr,
                                  int* __restrict__ bsums) {
    __shared__ int buf[SCAN_CHUNK];
    int base = blockIdx.x * SCAN_CHUNK;
    int i = base + threadIdx.x;
    buf[threadIdx.x] = (i < N_NODES) ? deg[i] : 0;
    __syncthreads();
    for (int off = 1; off < SCAN_CHUNK; off <<= 1) {
        int t = (threadIdx.x >= off) ? buf[threadIdx.x - off] : 0;
        __syncthreads();
        buf[threadIdx.x] += t;
        __syncthreads();
    }
    if (i < N_NODES) row_ptr[i + 1] = buf[threadIdx.x];   // local inclusive
    if (threadIdx.x == SCAN_CHUNK - 1) bsums[blockIdx.x] = buf[SCAN_CHUNK - 1];
    if (blockIdx.x == 0 && threadIdx.x == 0) row_ptr[0] = 0;
}

// stage 2: exclusive scan of the 49 chunk totals
__global__ void scan_bsums_kernel(int* __restrict__ bsums) {
    __shared__ int buf[64];
    int i = threadIdx.x;
    buf[i] = (i < N_CHUNKS) ? bsums[i] : 0;
    __syncthreads();
    for (int off = 1; off < 64; off <<= 1) {
        int t = (i >= off) ? buf[i - off] : 0;
        __syncthreads();
        buf[i] += t;
        __syncthreads();
    }
    if (i < N_CHUNKS) bsums[i] = (i == 0) ? 0 : buf[i - 1];
}

// stage 3: add chunk offsets
__global__ void scan_add_kernel(int* __restrict__ row_ptr, const int* __restrict__ bsums) {
    int i = blockIdx.x * blockDim.x + threadIdx.x;
    if (i < N_NODES) row_ptr[i + 1] += bsums[i / SCAN_CHUNK];
}

__global__ void copy_int_kernel(const int* __restrict__ a, int* __restrict__ b, int n) {
    int i = blockIdx.x * blockDim.x + threadIdx.x;
    if (i < n) b[i] = a[i];
}

__global__ void scatter_kernel(const int* __restrict__ ei, const int* __restrict__ flag,
                               int* __restrict__ cursor, int* __restrict__ csr_src) {
    int e = blockIdx.x * blockDim.x + threadIdx.x;
    if (e >= E_TOT) return;
    int s, d;
    get_edge(ei, flag[0], e, s, d);
    int pos = atomicAdd(&cursor[d], 1);
    csr_src[pos] = s;
}

// ================= GEMMs: tile 128x64, 256 threads, 8x4 micro-tile =================
__global__ void __launch_bounds__(256) gemm128_kernel(
        const float* __restrict__ A, const float* __restrict__ B,
        float* __restrict__ C, int M, int K, int ldb, int bcol) {
    __shared__ float As[16][132];
    __shared__ float Bs[16][68];
    const int row0 = blockIdx.x * 128;
    const int tid = threadIdx.x;
    const int tm = (tid >> 4) * 8;
    const int tn = (tid & 15) * 4;
    float acc[8][4] = {};
    for (int k0 = 0; k0 < K; k0 += 16) {
        #pragma unroll
        for (int r = 0; r < 2; r++) {
            int idx = tid * 2 + r;
            int m = idx >> 2;
            int q = (idx & 3) * 4;
            int gm = row0 + m;
            float4 v = make_float4(0.f, 0.f, 0.f, 0.f);
            if (gm < M) v = *(const float4*)(A + (size_t)gm * K + k0 + q);
            As[q + 0][m] = v.x; As[q + 1][m] = v.y; As[q + 2][m] = v.z; As[q + 3][m] = v.w;
        }
        {
            int k = tid >> 4;
            int n = (tid & 15) * 4;
            *(float4*)&Bs[k][n] = *(const float4*)(B + (size_t)(k0 + k) * ldb + bcol + n);
        }
        __syncthreads();
        #pragma unroll
        for (int k = 0; k < 16; k++) {
            float a[8], b[4];
            #pragma unroll
            for (int i = 0; i < 8; i++) a[i] = As[k][tm + i];
            #pragma unroll
            for (int j = 0; j < 4; j++) b[j] = Bs[k][tn + j];
            #pragma unroll
            for (int i = 0; i < 8; i++)
                #pragma unroll
                for (int j = 0; j < 4; j++) acc[i][j] += a[i] * b[j];
        }
        __syncthreads();
    }
    #pragma unroll
    for (int i = 0; i < 8; i++) {
        int gm = row0 + tm + i;
        if (gm < M)
            *(float4*)(C + (size_t)gm * 64 + tn) =
                make_float4(acc[i][0], acc[i][1], acc[i][2], acc[i][3]);
    }
}

// C(f32)[M,64] += elu(agg + bias) @ W2[brow:brow+64, :]
__global__ void __launch_bounds__(256) gemm128_acc_elu_kernel(
        const float* __restrict__ agg, const float* __restrict__ bias,
        const float* __restrict__ B, float* __restrict__ C, int M, int brow) {
    __shared__ float As[16][132];
    __shared__ float Bs[16][68];
    const int row0 = blockIdx.x * 128;
    const int tid = threadIdx.x;
    const int tm = (tid >> 4) * 8;
    const int tn = (tid & 15) * 4;
    float acc[8][4] = {};
    for (int k0 = 0; k0 < 64; k0 += 16) {
        #pragma unroll
        for (int r = 0; r < 2; r++) {
            int idx = tid * 2 + r;
            int m = idx >> 2;
            int q = (idx & 3) * 4;
            int gm = row0 + m;
            float4 v = make_float4(0.f, 0.f, 0.f, 0.f);
            if (gm < M) {
                v = *(const float4*)(agg + (size_t)gm * 64 + k0 + q);
                float4 bb = *(const float4*)(bias + k0 + q);
                v.x += bb.x; v.y += bb.y; v.z += bb.z; v.w += bb.w;
                v.x = (v.x > 0.f) ? v.x : expm1f(v.x);
                v.y = (v.y > 0.f) ? v.y : expm1f(v.y);
                v.z = (v.z > 0.f) ? v.z : expm1f(v.z);
                v.w = (v.w > 0.f) ? v.w : expm1f(v.w);
            }
            As[q + 0][m] = v.x; As[q + 1][m] = v.y; As[q + 2][m] = v.z; As[q + 3][m] = v.w;
        }
        {
            int k = tid >> 4;
            int n = (tid & 15) * 4;
            *(float4*)&Bs[k][n] = *(const float4*)(B + (size_t)(brow + k0 + k) * 64 + n);
        }
        __syncthreads();
        #pragma unroll
        for (int k = 0; k < 16; k++) {
            float a[8], b[4];
            #pragma unroll
            for (int i = 0; i < 8; i++) a[i] = As[k][tm + i];
            #pragma unroll
            for (int j = 0; j < 4; j++) b[j] = Bs[k][tn + j];
            #pragma unroll
            for (int i = 0; i < 8; i++)
                #pragma unroll
                for (int j = 0; j < 4; j++) acc[i][j] += a[i] * b[j];
        }
        __syncthreads();
    }
    #pragma unroll
    for (int i = 0; i < 8; i++) {
        int gm = row0 + tm + i;
        if (gm < M) {
            float4 c = *(float4*)(C + (size_t)gm * 64 + tn);
            c.x += acc[i][0]; c.y += acc[i][1]; c.z += acc[i][2]; c.w += acc[i][3];
            *(float4*)(C + (size_t)gm * 64 + tn) = c;
        }
    }
}

// ---- attention scores (single head), float4 loads ----
__global__ void attn_score_kernel(const float* __restrict__ hfeat,
                                  const float* __restrict__ att_s,
                                  const float* __restrict__ att_d,
                                  float* __restrict__ as_, float* __restrict__ ad_) {
    int n = blockIdx.x * blockDim.x + threadIdx.x;
    if (n >= N_NODES) return;
    const float4* row = (const float4*)(hfeat + (size_t)n * HIDDEN);
    const float4* aS = (const float4*)att_s;
    const float4* aD = (const float4*)att_d;
    float s = 0.f, d = 0.f;
    #pragma unroll
    for (int c = 0; c < HIDDEN / 4; c++) {
        float4 v = row[c], a = aS[c], b = aD[c];
        s += v.x * a.x + v.y * a.y + v.z * a.z + v.w * a.w;
        d += v.x * b.x + v.y * b.y + v.z * b.z + v.w * b.w;
    }
    as_[n] = s;
    ad_[n] = d;
}

// ========== softmax stats: thread per node -> per-edge weight w, per-node 1/l ==========
__global__ void softmax_stats_kernel(const int* __restrict__ row_ptr,
                                     const int* __restrict__ csr_src,
                                     const float* __restrict__ as_,
                                     const float* __restrict__ ad_,
                                     float* __restrict__ wbuf,
                                     float* __restrict__ inv_l) {
    int n = blockIdx.x * blockDim.x + threadIdx.x;
    if (n >= N_NODES) return;
    int b = row_ptr[n], e = row_ptr[n + 1];
    float adn = ad_[n];
    float m = -INFINITY;
    for (int j = b; j < e; j++) {
        float v = as_[csr_src[j]] + adn;
        v = (v > 0.f) ? v : NEG_SLOPE * v;
        m = fmaxf(m, v);
    }
    float l = 0.f;
    for (int j = b; j < e; j++) {
        float v = as_[csr_src[j]] + adn;
        v = (v > 0.f) ? v : NEG_SLOPE * v;
        float p = __expf(v - m);
        wbuf[j] = p;
        l += p;
    }
    inv_l[n] = 1.f / (l + 1e-16f);
}

// ========== gather: wave per node, independent FMA iterations, unroll x4 ==========
__global__ void __launch_bounds__(256) gat_gather_kernel(
        const int* __restrict__ row_ptr, const int* __restrict__ csr_src,
        const float* __restrict__ wbuf, const float* __restrict__ inv_l,
        const float* __restrict__ hfeat, float* __restrict__ agg) {
    int wave = threadIdx.x >> 6;
    int c    = threadIdx.x & 63;
    int n    = blockIdx.x * 4 + wave;
    if (n >= N_NODES) return;
    int b = row_ptr[n], e = row_ptr[n + 1];
    float a0 = 0.f, a1 = 0.f, a2 = 0.f, a3 = 0.f;
    int j = b;
    for (; j + 4 <= e; j += 4) {
        int s0 = csr_src[j], s1 = csr_src[j + 1], s2 = csr_src[j + 2], s3 = csr_src[j + 3];
        float w0 = wbuf[j], w1 = wbuf[j + 1], w2 = wbuf[j + 2], w3 = wbuf[j + 3];
        float h0 = hfeat[(size_t)s0 * HIDDEN + c];
        float h1 = hfeat[(size_t)s1 * HIDDEN + c];
        float h2 = hfeat[(size_t)s2 * HIDDEN + c];
        float h3 = hfeat[(size_t)s3 * HIDDEN + c];
        a0 += w0 * h0; a1 += w1 * h1; a2 += w2 * h2; a3 += w3 * h3;
    }
    for (; j < e; j++) {
        a0 += wbuf[j] * hfeat[(size_t)csr_src[j] * HIDDEN + c];
    }
    agg[(size_t)n * HIDDEN + c] = (a0 + a1 + a2 + a3) * inv_l[n];
}

// ---- fused: out = (elu(agg + b2)) @ Wout + bout ----
__global__ void out_linear_elu_kernel(const float* __restrict__ agg,
                                      const float* __restrict__ bias,
                                      const float* __restrict__ Wout,
                                      const float* __restrict__ bout,
                                      float* __restrict__ out) {
    int n = blockIdx.x * blockDim.x + threadIdx.x;
    if (n >= N_NODES) return;
    float a0 = bout[0], a1 = bout[1], a2 = bout[2];
    for (int c = 0; c < HIDDEN; c++) {
        float v = agg[(size_t)n * HIDDEN + c] + bias[c];
        v = (v > 0.f) ? v : expm1f(v);
        a0 += v * Wout[c * OUT_DIM + 0];
        a1 += v * Wout[c * OUT_DIM + 1];
        a2 += v * Wout[c * OUT_DIM + 2];
    }
    out[n * OUT_DIM + 0] = a0;
    out[n * OUT_DIM + 1] = a1;
    out[n * OUT_DIM + 2] = a2;
}

extern "C" void kernel_launch(void* const* d_in, const int* in_sizes, int n_in,
                              void* d_out, int out_size, void* d_ws, size_t ws_size,
                              hipStream_t stream) {
    const float* x    = (const float*)d_in[0];
    const int*   ei   = (const int*)d_in[1];
    const float* W1   = (const float*)d_in[2];
    const float* as1  = (const float*)d_in[3];
    const float* ad1  = (const float*)d_in[4];
    const float* b1   = (const float*)d_in[5];
    const float* W2   = (const float*)d_in[6];
    const float* as2  = (const float*)d_in[7];
    const float* ad2  = (const float*)d_in[8];
    const float* b2v  = (const float*)d_in[9];
    const float* Wout = (const float*)d_in[10];
    const float* bout = (const float*)d_in[11];
    float* out = (float*)d_out;

    // ---- workspace layout (~45 MB), flag at base ----
    float* ws   = (float*)d_ws;
    int*   flag = (int*)ws;                          // 16 floats reserved
    float* asb  = ws + 16;                           // 50,000
    float* adb  = asb + N_NODES;                     // 50,000
    float* ilb  = adb + N_NODES;                     // 50,000 (inv_l)
    float* wbuf = ilb + N_NODES;                     // 450,000 (per-edge weights)
    float* h1h  = wbuf + E_TOT;                      // 3,200,000 (per-head feats)
    float* aggh = h1h + (size_t)N_NODES * HIDDEN;    // 3,200,000 (per-head agg)
    float* h2   = aggh + (size_t)N_NODES * HIDDEN;   // 3,200,000 (accumulated L2 features)
    int* deg     = (int*)(h2 + (size_t)N_NODES * HIDDEN);  // 50,000 (also scatter cursor)
    int* row_ptr = deg + N_NODES;                    // 50,001 (+pad)
    int* csr_src = row_ptr + N_NODES + 16;           // 450,000
    int* bsums   = csr_src + E_TOT;                  // 64

    const int EB = (E_TOT + 255) / 256;
    const int NB = (N_NODES + 255) / 256;
    const int GB = (N_NODES + 127) / 128;
    const int AB = (N_NODES + 3) / 4;

    detect_int64_kernel<<<1, 256, 0, stream>>>(ei, flag);
    hipMemsetAsync(h2, 0, (size_t)N_NODES * HIDDEN * sizeof(float), stream);

    // ---- CSR build ----
    hipMemsetAsync(deg, 0, (size_t)N_NODES * sizeof(int), stream);
    count_deg_kernel<<<EB, 256, 0, stream>>>(ei, flag, deg);
    scan_local_kernel<<<N_CHUNKS, SCAN_CHUNK, 0, stream>>>(deg, row_ptr, bsums);
    scan_bsums_kernel<<<1, 64, 0, stream>>>(bsums);
    scan_add_kernel<<<NB, 256, 0, stream>>>(row_ptr, bsums);
    copy_int_kernel<<<NB, 256, 0, stream>>>(row_ptr, deg, N_NODES);
    scatter_kernel<<<EB, 256, 0, stream>>>(ei, flag, deg, csr_src);

    // ===== layer 1 per head (GATConv 128 -> 64, heads=4), fused into L2-input GEMM =====
    for (int h = 0; h < HEADS1; h++) {
        gemm128_kernel<<<GB, 256, 0, stream>>>(x, W1, h1h, N_NODES, IN_DIM, HEADS1 * HIDDEN, h * HIDDEN);
        attn_score_kernel<<<NB, 256, 0, stream>>>(h1h, as1 + h * HIDDEN, ad1 + h * HIDDEN, asb, adb);
        softmax_stats_kernel<<<NB, 256, 0, stream>>>(row_ptr, csr_src, asb, adb, wbuf, ilb);
        gat_gather_kernel<<<AB, 256, 0, stream>>>(row_ptr, csr_src, wbuf, ilb, h1h, aggh);
        gemm128_acc_elu_kernel<<<GB, 256, 0, stream>>>(aggh, b1 + h * HIDDEN, W2, h2, N_NODES, h * HIDDEN);
    }

    // ===== layer 2 (GATConv 256 -> 64, heads=1) =====
    attn_score_kernel<<<NB, 256, 0, stream>>>(h2, as2, ad2, asb, adb);
    softmax_stats_kernel<<<NB, 256, 0, stream>>>(row_ptr, csr_src, asb, adb, wbuf, ilb);
    gat_gather_kernel<<<AB, 256, 0, stream>>>(row_ptr, csr_src, wbuf, ilb, h2, aggh);

    // ===== fused elu + output projection =====
    out_linear_elu_kernel<<<NB, 256, 0, stream>>>(aggh, b2v, Wout, bout, out);
}

// Round 8
// 397.195 us; speedup vs baseline: 4.6921x; 1.3883x over previous
//
#include <hip/hip_runtime.h>
#include <hip/hip_bf16.h>
#include <math.h>

#define N_NODES  50000
#define IN_DIM   128
#define HIDDEN   64
#define OUT_DIM  3
#define HEADS1   4
#define E_RAW    400000
#define E_TOT    450000   // raw edges + one self loop per node
#define NEG_SLOPE 0.2f
#define SCAN_CHUNK 1024
#define N_CHUNKS ((N_NODES + SCAN_CHUNK - 1) / SCAN_CHUNK)   // 49

// ---- edge fetch, robust to int32 vs int64 storage, indices clamped ----
static __device__ __forceinline__ void get_edge(const int* __restrict__ ei, int is64,
                                                int e, int& s, int& d) {
    if (e >= E_RAW) { s = d = e - E_RAW; return; }   // self loop
    if (is64) { s = ei[2 * e]; d = ei[2 * E_RAW + 2 * e]; }
    else      { s = ei[e];     d = ei[E_RAW + e]; }
    s = min(max(s, 0), N_NODES - 1);
    d = min(max(d, 0), N_NODES - 1);
}

// Detect int64 storage: high words of int64 pairs are all 0 for values < 2^31.
__global__ void detect_int64_kernel(const int* __restrict__ ei, int* __restrict__ flag) {
    __shared__ int any_nonzero;
    if (threadIdx.x == 0) any_nonzero = 0;
    __syncthreads();
    for (int i = threadIdx.x; i < 8192; i += blockDim.x) {
        int k = i * 48;                    // 2k+1 < 786,433: in-bounds for both layouts
        if (ei[2 * k + 1] != 0) any_nonzero = 1;   // benign race
    }
    __syncthreads();
    if (threadIdx.x == 0) flag[0] = (any_nonzero == 0) ? 1 : 0;
}

// ================= CSR construction (once per launch, graph is static) =================
__global__ void count_deg_kernel(const int* __restrict__ ei, const int* __restrict__ flag,
                                 int* __restrict__ deg) {
    int e = blockIdx.x * blockDim.x + threadIdx.x;
    if (e >= E_TOT) return;
    int s, d;
    get_edge(ei, flag[0], e, s, d);
    atomicAdd(&deg[d], 1);
}

__global__ void scan_local_kernel(const int* __restrict__ deg, int* __restrict__ row_ptr,
                                  int* __restrict__ bsums) {
    __shared__ int buf[SCAN_CHUNK];
    int base = blockIdx.x * SCAN_CHUNK;
    int i = base + threadIdx.x;
    buf[threadIdx.x] = (i < N_NODES) ? deg[i] : 0;
    __syncthreads();
    for (int off = 1; off < SCAN_CHUNK; off <<= 1) {
        int t = (threadIdx.x >= off) ? buf[threadIdx.x - off] : 0;
        __syncthreads();
        buf[threadIdx.x] += t;
        __syncthreads();
    }
    if (i < N_NODES) row_ptr[i + 1] = buf[threadIdx.x];
    if (threadIdx.x == SCAN_CHUNK - 1) bsums[blockIdx.x] = buf[SCAN_CHUNK - 1];
    if (blockIdx.x == 0 && threadIdx.x == 0) row_ptr[0] = 0;
}

__global__ void scan_bsums_kernel(int* __restrict__ bsums) {
    __shared__ int buf[64];
    int i = threadIdx.x;
    buf[i] = (i < N_CHUNKS) ? bsums[i] : 0;
    __syncthreads();
    for (int off = 1; off < 64; off <<= 1) {
        int t = (i >= off) ? buf[i - off] : 0;
        __syncthreads();
        buf[i] += t;
        __syncthreads();
    }
    if (i < N_CHUNKS) bsums[i] = (i == 0) ? 0 : buf[i - 1];
}

__global__ void scan_add_kernel(int* __restrict__ row_ptr, const int* __restrict__ bsums) {
    int i = blockIdx.x * blockDim.x + threadIdx.x;
    if (i < N_NODES) row_ptr[i + 1] += bsums[i / SCAN_CHUNK];
}

__global__ void copy_int_kernel(const int* __restrict__ a, int* __restrict__ b, int n) {
    int i = blockIdx.x * blockDim.x + threadIdx.x;
    if (i < n) b[i] = a[i];
}

__global__ void scatter_kernel(const int* __restrict__ ei, const int* __restrict__ flag,
                               int* __restrict__ cursor, int* __restrict__ csr_src) {
    int e = blockIdx.x * blockDim.x + threadIdx.x;
    if (e >= E_TOT) return;
    int s, d;
    get_edge(ei, flag[0], e, s, d);
    int pos = atomicAdd(&cursor[d], 1);
    csr_src[pos] = s;
}

// ========== layer-1 GEMM (all heads) + fused attention scores ==========
// h1[M,256] = x[M,128] @ W1[128,256]; per 64-col tile == one head:
// asb[m*4+h] = <h1[m, h*64:h*64+64], att_s[h]>, adb likewise (shfl reduction).
__global__ void __launch_bounds__(256) gemm_l1_kernel(
        const float* __restrict__ A, const float* __restrict__ B,
        const float* __restrict__ att_s, const float* __restrict__ att_d,
        float* __restrict__ C, float* __restrict__ asb, float* __restrict__ adb, int M) {
    __shared__ float As[16][132];
    __shared__ float Bs[16][68];
    const int head = blockIdx.y;
    const int bcol = head * 64;
    const int row0 = blockIdx.x * 128;
    const int tid = threadIdx.x;
    const int tm = (tid >> 4) * 8;
    const int tn = (tid & 15) * 4;
    float acc[8][4] = {};
    for (int k0 = 0; k0 < IN_DIM; k0 += 16) {
        #pragma unroll
        for (int r = 0; r < 2; r++) {
            int idx = tid * 2 + r;
            int m = idx >> 2;
            int q = (idx & 3) * 4;
            int gm = row0 + m;
            float4 v = make_float4(0.f, 0.f, 0.f, 0.f);
            if (gm < M) v = *(const float4*)(A + (size_t)gm * IN_DIM + k0 + q);
            As[q + 0][m] = v.x; As[q + 1][m] = v.y; As[q + 2][m] = v.z; As[q + 3][m] = v.w;
        }
        {
            int k = tid >> 4;
            int n = (tid & 15) * 4;
            *(float4*)&Bs[k][n] = *(const float4*)(B + (size_t)(k0 + k) * 256 + bcol + n);
        }
        __syncthreads();
        #pragma unroll
        for (int k = 0; k < 16; k++) {
            float a[8], b[4];
            #pragma unroll
            for (int i = 0; i < 8; i++) a[i] = As[k][tm + i];
            #pragma unroll
            for (int j = 0; j < 4; j++) b[j] = Bs[k][tn + j];
            #pragma unroll
            for (int i = 0; i < 8; i++)
                #pragma unroll
                for (int j = 0; j < 4; j++) acc[i][j] += a[i] * b[j];
        }
        __syncthreads();
    }
    float4 ats = *(const float4*)(att_s + bcol + tn);
    float4 atd = *(const float4*)(att_d + bcol + tn);
    #pragma unroll
    for (int i = 0; i < 8; i++) {
        int gm = row0 + tm + i;
        float ps = acc[i][0] * ats.x + acc[i][1] * ats.y + acc[i][2] * ats.z + acc[i][3] * ats.w;
        float pd = acc[i][0] * atd.x + acc[i][1] * atd.y + acc[i][2] * atd.z + acc[i][3] * atd.w;
        #pragma unroll
        for (int off = 1; off < 16; off <<= 1) {
            ps += __shfl_xor(ps, off, 16);
            pd += __shfl_xor(pd, off, 16);
        }
        if (gm < M) {
            *(float4*)(C + (size_t)gm * 256 + bcol + tn) =
                make_float4(acc[i][0], acc[i][1], acc[i][2], acc[i][3]);
            if ((tid & 15) == 0) { asb[gm * 4 + head] = ps; adb[gm * 4 + head] = pd; }
        }
    }
}

// ========== layer-2 GEMM: h2[M,64] = elu(agg1[M,256]+b1) @ W2[256,64], attn fused ==========
__global__ void __launch_bounds__(256) gemm_l2_kernel(
        const float* __restrict__ agg, const float* __restrict__ bias,
        const float* __restrict__ B,
        const float* __restrict__ att_s, const float* __restrict__ att_d,
        float* __restrict__ C, float* __restrict__ asb, float* __restrict__ adb, int M) {
    __shared__ float As[16][132];
    __shared__ float Bs[16][68];
    const int row0 = blockIdx.x * 128;
    const int tid = threadIdx.x;
    const int tm = (tid >> 4) * 8;
    const int tn = (tid & 15) * 4;
    float acc[8][4] = {};
    for (int k0 = 0; k0 < 256; k0 += 16) {
        #pragma unroll
        for (int r = 0; r < 2; r++) {
            int idx = tid * 2 + r;
            int m = idx >> 2;
            int q = (idx & 3) * 4;
            int gm = row0 + m;
            float4 v = make_float4(0.f, 0.f, 0.f, 0.f);
            if (gm < M) {
                v = *(const float4*)(agg + (size_t)gm * 256 + k0 + q);
                float4 bb = *(const float4*)(bias + k0 + q);
                v.x += bb.x; v.y += bb.y; v.z += bb.z; v.w += bb.w;
                v.x = (v.x > 0.f) ? v.x : expm1f(v.x);
                v.y = (v.y > 0.f) ? v.y : expm1f(v.y);
                v.z = (v.z > 0.f) ? v.z : expm1f(v.z);
                v.w = (v.w > 0.f) ? v.w : expm1f(v.w);
            }
            As[q + 0][m] = v.x; As[q + 1][m] = v.y; As[q + 2][m] = v.z; As[q + 3][m] = v.w;
        }
        {
            int k = tid >> 4;
            int n = (tid & 15) * 4;
            *(float4*)&Bs[k][n] = *(const float4*)(B + (size_t)(k0 + k) * 64 + n);
        }
        __syncthreads();
        #pragma unroll
        for (int k = 0; k < 16; k++) {
            float a[8], b[4];
            #pragma unroll
            for (int i = 0; i < 8; i++) a[i] = As[k][tm + i];
            #pragma unroll
            for (int j = 0; j < 4; j++) b[j] = Bs[k][tn + j];
            #pragma unroll
            for (int i = 0; i < 8; i++)
                #pragma unroll
                for (int j = 0; j < 4; j++) acc[i][j] += a[i] * b[j];
        }
        __syncthreads();
    }
    float4 ats = *(const float4*)(att_s + tn);
    float4 atd = *(const float4*)(att_d + tn);
    #pragma unroll
    for (int i = 0; i < 8; i++) {
        int gm = row0 + tm + i;
        float ps = acc[i][0] * ats.x + acc[i][1] * ats.y + acc[i][2] * ats.z + acc[i][3] * ats.w;
        float pd = acc[i][0] * atd.x + acc[i][1] * atd.y + acc[i][2] * atd.z + acc[i][3] * atd.w;
        #pragma unroll
        for (int off = 1; off < 16; off <<= 1) {
            ps += __shfl_xor(ps, off, 16);
            pd += __shfl_xor(pd, off, 16);
        }
        if (gm < M) {
            *(float4*)(C + (size_t)gm * 64 + tn) =
                make_float4(acc[i][0], acc[i][1], acc[i][2], acc[i][3]);
            if ((tid & 15) == 0) { asb[gm] = ps; adb[gm] = pd; }
        }
    }
}

// ========== softmax stats, 4 heads at once (float4 per edge) ==========
__global__ void softmax_stats4_kernel(const int* __restrict__ row_ptr,
                                      const int* __restrict__ csr_src,
                                      const float* __restrict__ asb4,
                                      const float* __restrict__ adb4,
                                      float* __restrict__ wbuf,
                                      float* __restrict__ inv_l) {
    int n = blockIdx.x * blockDim.x + threadIdx.x;
    if (n >= N_NODES) return;
    int b = row_ptr[n], e = row_ptr[n + 1];
    float4 adn = ((const float4*)adb4)[n];
    float4 m = make_float4(-INFINITY, -INFINITY, -INFINITY, -INFINITY);
    for (int j = b; j < e; j++) {
        int s = csr_src[j];
        float4 v = ((const float4*)asb4)[s];
        v.x += adn.x; v.y += adn.y; v.z += adn.z; v.w += adn.w;
        v.x = (v.x > 0.f) ? v.x : NEG_SLOPE * v.x;
        v.y = (v.y > 0.f) ? v.y : NEG_SLOPE * v.y;
        v.z = (v.z > 0.f) ? v.z : NEG_SLOPE * v.z;
        v.w = (v.w > 0.f) ? v.w : NEG_SLOPE * v.w;
        ((float4*)wbuf)[j] = v;
        m.x = fmaxf(m.x, v.x); m.y = fmaxf(m.y, v.y);
        m.z = fmaxf(m.z, v.z); m.w = fmaxf(m.w, v.w);
    }
    float4 l = make_float4(0.f, 0.f, 0.f, 0.f);
    for (int j = b; j < e; j++) {
        float4 v = ((const float4*)wbuf)[j];
        float4 p;
        p.x = __expf(v.x - m.x); p.y = __expf(v.y - m.y);
        p.z = __expf(v.z - m.z); p.w = __expf(v.w - m.w);
        ((float4*)wbuf)[j] = p;
        l.x += p.x; l.y += p.y; l.z += p.z; l.w += p.w;
    }
    float4 il;
    il.x = 1.f / (l.x + 1e-16f); il.y = 1.f / (l.y + 1e-16f);
    il.z = 1.f / (l.z + 1e-16f); il.w = 1.f / (l.w + 1e-16f);
    ((float4*)inv_l)[n] = il;
}

// ---- single-head stats (layer 2), pass-2 reads staged wbuf ----
__global__ void softmax_stats1_kernel(const int* __restrict__ row_ptr,
                                      const int* __restrict__ csr_src,
                                      const float* __restrict__ as_,
                                      const float* __restrict__ ad_,
                                      float* __restrict__ wbuf,
                                      float* __restrict__ inv_l) {
    int n = blockIdx.x * blockDim.x + threadIdx.x;
    if (n >= N_NODES) return;
    int b = row_ptr[n], e = row_ptr[n + 1];
    float adn = ad_[n];
    float m = -INFINITY;
    for (int j = b; j < e; j++) {
        float v = as_[csr_src[j]] + adn;
        v = (v > 0.f) ? v : NEG_SLOPE * v;
        wbuf[j] = v;
        m = fmaxf(m, v);
    }
    float l = 0.f;
    for (int j = b; j < e; j++) {
        float p = __expf(wbuf[j] - m);
        wbuf[j] = p;
        l += p;
    }
    inv_l[n] = 1.f / (l + 1e-16f);
}

// ========== gather, 4 heads: one block per node, wave h handles head h ==========
__global__ void __launch_bounds__(256) gat_gather4_kernel(
        const int* __restrict__ row_ptr, const int* __restrict__ csr_src,
        const float* __restrict__ wbuf, const float* __restrict__ inv_l,
        const float* __restrict__ h1, float* __restrict__ agg) {
    int h = threadIdx.x >> 6;
    int c = threadIdx.x & 63;
    int n = blockIdx.x;
    int b = row_ptr[n], e = row_ptr[n + 1];
    float a0 = 0.f, a1 = 0.f, a2 = 0.f, a3 = 0.f;
    int j = b;
    for (; j + 4 <= e; j += 4) {
        int s0 = csr_src[j], s1 = csr_src[j + 1], s2 = csr_src[j + 2], s3 = csr_src[j + 3];
        float w0 = wbuf[(j + 0) * 4 + h], w1 = wbuf[(j + 1) * 4 + h];
        float w2 = wbuf[(j + 2) * 4 + h], w3 = wbuf[(j + 3) * 4 + h];
        float f0 = h1[(size_t)s0 * 256 + h * 64 + c];
        float f1 = h1[(size_t)s1 * 256 + h * 64 + c];
        float f2 = h1[(size_t)s2 * 256 + h * 64 + c];
        float f3 = h1[(size_t)s3 * 256 + h * 64 + c];
        a0 += w0 * f0; a1 += w1 * f1; a2 += w2 * f2; a3 += w3 * f3;
    }
    for (; j < e; j++) {
        a0 += wbuf[j * 4 + h] * h1[(size_t)csr_src[j] * 256 + h * 64 + c];
    }
    agg[(size_t)n * 256 + h * 64 + c] = (a0 + a1 + a2 + a3) * inv_l[n * 4 + h];
}

// ---- single-head gather (layer 2): 4 nodes per block ----
__global__ void __launch_bounds__(256) gat_gather1_kernel(
        const int* __restrict__ row_ptr, const int* __restrict__ csr_src,
        const float* __restrict__ wbuf, const float* __restrict__ inv_l,
        const float* __restrict__ hfeat, float* __restrict__ agg) {
    int wave = threadIdx.x >> 6;
    int c    = threadIdx.x & 63;
    int n    = blockIdx.x * 4 + wave;
    if (n >= N_NODES) return;
    int b = row_ptr[n], e = row_ptr[n + 1];
    float a0 = 0.f, a1 = 0.f, a2 = 0.f, a3 = 0.f;
    int j = b;
    for (; j + 4 <= e; j += 4) {
        int s0 = csr_src[j], s1 = csr_src[j + 1], s2 = csr_src[j + 2], s3 = csr_src[j + 3];
        float w0 = wbuf[j], w1 = wbuf[j + 1], w2 = wbuf[j + 2], w3 = wbuf[j + 3];
        float f0 = hfeat[(size_t)s0 * HIDDEN + c];
        float f1 = hfeat[(size_t)s1 * HIDDEN + c];
        float f2 = hfeat[(size_t)s2 * HIDDEN + c];
        float f3 = hfeat[(size_t)s3 * HIDDEN + c];
        a0 += w0 * f0; a1 += w1 * f1; a2 += w2 * f2; a3 += w3 * f3;
    }
    for (; j < e; j++) {
        a0 += wbuf[j] * hfeat[(size_t)csr_src[j] * HIDDEN + c];
    }
    agg[(size_t)n * HIDDEN + c] = (a0 + a1 + a2 + a3) * inv_l[n];
}

// ---- fused: out = (elu(agg + b2)) @ Wout + bout ----
__global__ void out_linear_elu_kernel(const float* __restrict__ agg,
                                      const float* __restrict__ bias,
                                      const float* __restrict__ Wout,
                                      const float* __restrict__ bout,
                                      float* __restrict__ out) {
    int n = blockIdx.x * blockDim.x + threadIdx.x;
    if (n >= N_NODES) return;
    float a0 = bout[0], a1 = bout[1], a2 = bout[2];
    for (int c = 0; c < HIDDEN; c++) {
        float v = agg[(size_t)n * HIDDEN + c] + bias[c];
        v = (v > 0.f) ? v : expm1f(v);
        a0 += v * Wout[c * OUT_DIM + 0];
        a1 += v * Wout[c * OUT_DIM + 1];
        a2 += v * Wout[c * OUT_DIM + 2];
    }
    out[n * OUT_DIM + 0] = a0;
    out[n * OUT_DIM + 1] = a1;
    out[n * OUT_DIM + 2] = a2;
}

extern "C" void kernel_launch(void* const* d_in, const int* in_sizes, int n_in,
                              void* d_out, int out_size, void* d_ws, size_t ws_size,
                              hipStream_t stream) {
    const float* x    = (const float*)d_in[0];
    const int*   ei   = (const int*)d_in[1];
    const float* W1   = (const float*)d_in[2];
    const float* as1  = (const float*)d_in[3];
    const float* ad1  = (const float*)d_in[4];
    const float* b1   = (const float*)d_in[5];
    const float* W2   = (const float*)d_in[6];
    const float* as2  = (const float*)d_in[7];
    const float* ad2  = (const float*)d_in[8];
    const float* b2v  = (const float*)d_in[9];
    const float* Wout = (const float*)d_in[10];
    const float* bout = (const float*)d_in[11];
    float* out = (float*)d_out;

    // ---- workspace layout (~130 MB; ws_size is 256 MiB per harness fill), flag at base ----
    float* ws    = (float*)d_ws;
    int*   flag  = (int*)ws;                          // 16 floats reserved
    float* asb4  = ws + 16;                           // 200,000 [N,4]
    float* adb4  = asb4 + (size_t)N_NODES * 4;        // 200,000
    float* ilb4  = adb4 + (size_t)N_NODES * 4;        // 200,000
    float* asb1  = ilb4 + (size_t)N_NODES * 4;        // 50,000
    float* adb1  = asb1 + N_NODES;                    // 50,000
    float* ilb1  = adb1 + N_NODES;                    // 50,000
    float* wbuf  = ilb1 + N_NODES;                    // 1,800,000 [E,4] (layer2 uses [E])
    float* h1    = wbuf + (size_t)E_TOT * 4;          // 12,800,000 [N,256]
    float* agg1  = h1 + (size_t)N_NODES * 256;        // 12,800,000 [N,256]
    float* h2    = agg1 + (size_t)N_NODES * 256;      // 3,200,000 [N,64]
    float* agg2  = h1;                                // reuse (h1 dead after gemm_l2 inputs... see note)
    int* deg     = (int*)(h2 + (size_t)N_NODES * HIDDEN);  // 50,000 (also scatter cursor)
    int* row_ptr = deg + N_NODES;                     // 50,001 (+pad)
    int* csr_src = row_ptr + N_NODES + 16;            // 450,000
    int* bsums   = csr_src + E_TOT;                   // 64
    // note: gather1 reads h2 and writes agg2 (=h1 region); h1 is only read by gather4,
    // which completed before gemm_l2 produced h2. Safe.

    const int EB = (E_TOT + 255) / 256;
    const int NB = (N_NODES + 255) / 256;
    const int GB = (N_NODES + 127) / 128;
    const int AB = (N_NODES + 3) / 4;

    detect_int64_kernel<<<1, 256, 0, stream>>>(ei, flag);

    // ---- CSR build ----
    hipMemsetAsync(deg, 0, (size_t)N_NODES * sizeof(int), stream);
    count_deg_kernel<<<EB, 256, 0, stream>>>(ei, flag, deg);
    scan_local_kernel<<<N_CHUNKS, SCAN_CHUNK, 0, stream>>>(deg, row_ptr, bsums);
    scan_bsums_kernel<<<1, 64, 0, stream>>>(bsums);
    scan_add_kernel<<<NB, 256, 0, stream>>>(row_ptr, bsums);
    copy_int_kernel<<<NB, 256, 0, stream>>>(row_ptr, deg, N_NODES);
    scatter_kernel<<<EB, 256, 0, stream>>>(ei, flag, deg, csr_src);

    // ===== layer 1: GEMM(all heads)+attn, stats4, gather4 =====
    gemm_l1_kernel<<<dim3(GB, HEADS1), 256, 0, stream>>>(x, W1, as1, ad1, h1, asb4, adb4, N_NODES);
    softmax_stats4_kernel<<<NB, 256, 0, stream>>>(row_ptr, csr_src, asb4, adb4, wbuf, ilb4);
    gat_gather4_kernel<<<N_NODES, 256, 0, stream>>>(row_ptr, csr_src, wbuf, ilb4, h1, agg1);

    // ===== layer 2: GEMM K=256 (elu+bias fused, attn fused), stats1, gather1 =====
    gemm_l2_kernel<<<GB, 256, 0, stream>>>(agg1, b1, W2, as2, ad2, h2, asb1, adb1, N_NODES);
    softmax_stats1_kernel<<<NB, 256, 0, stream>>>(row_ptr, csr_src, asb1, adb1, wbuf, ilb1);
    gat_gather1_kernel<<<AB, 256, 0, stream>>>(row_ptr, csr_src, wbuf, ilb1, h2, agg2);

    // ===== fused elu + output projection =====
    out_linear_elu_kernel<<<NB, 256, 0, stream>>>(agg2, b2v, Wout, bout, out);
}